// Round 5
// baseline (346.968 us; speedup 1.0000x reference)
//
#include <hip/hip_runtime.h>
#include <math.h>
#include <stdint.h>

#define BB 256
#define TT 512
#define KK 20
#define START_TAG 18
#define STOP_TAG 19
#define NST 400
#define SEGSTRIDE 420        // 400 M + 20 col-exponents
#define WS_SEG_OFF 1024
#define TPW 12               // tasks per wave (5 lanes each, lanes 60-63 idle for compute)
#define NI 19                // global_load_lds instructions: ceil(1200 chunks / 64)

__device__ __forceinline__ float fexp2(float x){ float r; asm("v_exp_f32 %0, %1":"=v"(r):"v"(x)); return r; }
__device__ __forceinline__ float flog2(float x){ float r; asm("v_log_f32 %0, %1":"=v"(r):"v"(x)); return r; }

__device__ __forceinline__ void gll16(const void* g, void* l) {
    __builtin_amdgcn_global_load_lds(
        (const __attribute__((address_space(1))) void*)g,
        (__attribute__((address_space(3))) void*)l, 16, 0, 0);
}

// ============ pass 1: per-segment 20x20 matrix products ============
// 12 tasks/wave, 5 lanes/task, lane owns 4 columns of the running product.
// Features DMA'd global->LDS (16B gll) with chunk-rotation swizzle (k+g)%5;
// in-place exp2 pass (own rows); per-column pow2 renorm every 4 steps.
// SEGL=4 primary: ~2731 blocks -> ~2.7 waves/SIMD (TLP hides DMA+LDS latency).
template<int SEGL, int SEGS>
__global__ __launch_bounds__(64,2) void seg_kernel2(
    const float* __restrict__ feats, const int* __restrict__ lengths,
    float* __restrict__ wseg)
{
    constexpr int TASKS2 = BB*SEGS;
    constexpr float LOG2E = 1.4426950408889634f;
    const int lane = threadIdx.x;

    __shared__ __align__(16) float E[TPW*NST];   // 19200 B, chunk-swizzled

    // ---- compute role ----
    int g = lane / 5;
    int p = lane - 5*g;
    const bool alive = (g < TPW);
    const int gc = alive ? g : (TPW-1);
    int traw = blockIdx.x*TPW + gc;
    const bool real = alive && (traw < TASKS2);
    const int task = (traw < TASKS2) ? traw : (TASKS2-1);
    const int b = task / SEGS;
    const int s = task - b*SEGS;
    const int seg0 = 1 + SEGL*s;
    const int len = lengths[b];
    int nv_ = len - seg0; nv_ = nv_ < 0 ? 0 : (nv_ > SEGL ? SEGL : nv_);

    int itmax = nv_;
    #pragma unroll
    for (int o = 32; o > 0; o >>= 1){ int t2 = __shfl_xor(itmax, o, 64); itmax = t2 > itmax ? t2 : itmax; }
    if (itmax == 0) return;

    // ---- gll role: per-lane source offsets for 19 DMA instrs ----
    uint32_t cur[NI], lim[NI];
    #pragma unroll
    for (int m = 0; m < NI; ++m){
        int n = 64*m + lane;
        int nc = (n < TPW*100) ? n : 0;
        int gm = nc / 100;
        int rem = nc - 100*gm;
        int rm = rem / 5;
        int kp = rem - 5*rm;          // stored slot
        int km = kp - (gm % 5); if (km < 0) km += 5;   // logical chunk
        int tk = blockIdx.x*TPW + gm; if (tk >= TASKS2) tk = TASKS2-1;
        int bm = tk / SEGS, sm = tk - bm*SEGS;
        uint32_t base = ((uint32_t)bm*TT*NST + (uint32_t)(rm*20 + km*4)) * 4u;
        cur[m] = base + (uint32_t)(1 + SEGL*sm) * 1600u;
        lim[m] = base + 511u * 1600u;
    }

    const char* fB = (const char*)feats;
    // prologue: DMA E for it=0
    #pragma unroll
    for (int m = 0; m < NI; ++m){
        if (m < NI-1 || lane < (TPW*100 - 64*(NI-1)))
            gll16(fB + cur[m], (void*)&E[m*256]);
    }

    // read-slot offsets: logical chunk k lives at slot (k+gc)%5
    int koff[5];
    #pragma unroll
    for (int k = 0; k < 5; ++k){ int kp = k + (gc % 5); if (kp >= 5) kp -= 5; koff[k] = 4*kp; }
    const int rot = (p + gc) % 5;   // exp-pass row rotation (bank spread)

    float vA[20][4], vB[20][4];
    int cexp[4] = {0,0,0,0};
    #pragma unroll
    for (int j = 0; j < 20; ++j)
        #pragma unroll
        for (int cc = 0; cc < 4; ++cc) vA[j][cc] = (j == 4*p + cc) ? 1.f : 0.f;

    auto STEP = [&](float (&VIN)[20][4], float (&VOUT)[20][4], int it){
        asm volatile("s_waitcnt vmcnt(0)" ::: "memory");     // raw E_t landed
        // in-place exp2 of own 4 rows
        if (lane < 5*TPW){
            #pragma unroll
            for (int mm = 0; mm < 4; ++mm){
                int rr = 5*mm + rot;
                float* rp = &E[gc*NST + rr*20];
                #pragma unroll
                for (int k5 = 0; k5 < 5; ++k5){
                    float4 x = *(float4*)(rp + 4*k5);
                    x.x = fexp2(x.x*LOG2E); x.y = fexp2(x.y*LOG2E);
                    x.z = fexp2(x.z*LOG2E); x.w = fexp2(x.w*LOG2E);
                    *(float4*)(rp + 4*k5) = x;
                }
            }
        }
        asm volatile("s_waitcnt lgkmcnt(0)" ::: "memory");   // exp writes visible
        #pragma unroll
        for (int ii = 0; ii < 20; ++ii){
            const float* rb = &E[gc*NST + ii*20];
            float4 e0 = *(const float4*)(rb + koff[0]);
            float4 e1 = *(const float4*)(rb + koff[1]);
            float4 e2 = *(const float4*)(rb + koff[2]);
            float4 e3 = *(const float4*)(rb + koff[3]);
            float4 e4 = *(const float4*)(rb + koff[4]);
            #pragma unroll
            for (int cc = 0; cc < 4; ++cc){
                float s0 = e0.x*VIN[0][cc];
                float s1 = e0.y*VIN[1][cc];
                s0 = fmaf(e0.z, VIN[2][cc],  s0);  s1 = fmaf(e0.w, VIN[3][cc],  s1);
                s0 = fmaf(e1.x, VIN[4][cc],  s0);  s1 = fmaf(e1.y, VIN[5][cc],  s1);
                s0 = fmaf(e1.z, VIN[6][cc],  s0);  s1 = fmaf(e1.w, VIN[7][cc],  s1);
                s0 = fmaf(e2.x, VIN[8][cc],  s0);  s1 = fmaf(e2.y, VIN[9][cc],  s1);
                s0 = fmaf(e2.z, VIN[10][cc], s0);  s1 = fmaf(e2.w, VIN[11][cc], s1);
                s0 = fmaf(e3.x, VIN[12][cc], s0);  s1 = fmaf(e3.y, VIN[13][cc], s1);
                s0 = fmaf(e3.z, VIN[14][cc], s0);  s1 = fmaf(e3.w, VIN[15][cc], s1);
                s0 = fmaf(e4.x, VIN[16][cc], s0);  s1 = fmaf(e4.y, VIN[17][cc], s1);
                s0 = fmaf(e4.z, VIN[18][cc], s0);  s1 = fmaf(e4.w, VIN[19][cc], s1);
                VOUT[ii][cc] = s0 + s1;
            }
        }
        asm volatile("s_waitcnt lgkmcnt(0)" ::: "memory");   // all E reads retired
        if (it + 1 < itmax){                                 // DMA next step ASAP (before VALU tail)
            #pragma unroll
            for (int m = 0; m < NI; ++m){
                uint32_t nx = cur[m] + 1600u;
                cur[m] = nx > lim[m] ? lim[m] : nx;
                if (m < NI-1 || lane < (TPW*100 - 64*(NI-1)))
                    gll16(fB + cur[m], (void*)&E[m*256]);
            }
        }
        const bool ok = (it < nv_);                          // freeze finished tasks
        #pragma unroll
        for (int j = 0; j < 20; ++j)
            #pragma unroll
            for (int cc = 0; cc < 4; ++cc) VOUT[j][cc] = ok ? VOUT[j][cc] : VIN[j][cc];
        if ((it & 3) == 3){                                  // exact pow2 renorm
            #pragma unroll
            for (int cc = 0; cc < 4; ++cc){
                float mx = VOUT[0][cc];
                #pragma unroll
                for (int j = 1; j < 20; ++j) mx = fmaxf(mx, VOUT[j][cc]);
                int e = (int)((__float_as_uint(mx) >> 23) & 255) - 127;
                float sc = __uint_as_float((uint32_t)(127 - e) << 23);
                #pragma unroll
                for (int j = 0; j < 20; ++j) VOUT[j][cc] *= sc;
                cexp[cc] += e;
            }
        }
    };

    int it = 0;
    while (true){
        STEP(vA, vB, it); ++it;
        if (it >= itmax){
            #pragma unroll
            for (int j = 0; j < 20; ++j)
                #pragma unroll
                for (int cc = 0; cc < 4; ++cc) vA[j][cc] = vB[j][cc];
            break;
        }
        STEP(vB, vA, it); ++it;
        if (it >= itmax) break;
    }

    if (real && nv_ > 0){
        float* out = wseg + (size_t)task * SEGSTRIDE;
        #pragma unroll
        for (int ii = 0; ii < 20; ++ii)
            *(float4*)&out[ii*20 + 4*p] = make_float4(vA[ii][0], vA[ii][1], vA[ii][2], vA[ii][3]);
        int* oi = (int*)out;
        #pragma unroll
        for (int cc = 0; cc < 4; ++cc) oi[NST + 4*p + cc] = cexp[cc];
    }
}

// ============ pass 2: serial segment applications (<=SEGS steps) ============
template<int SEGL, int SEGS>
__global__ __launch_bounds__(64,1) void chain_kernel2(
    const float* __restrict__ feats, const float* __restrict__ trans,
    const int* __restrict__ targets, const int* __restrict__ lengths,
    const float* __restrict__ wseg, float* __restrict__ partialA)
{
    constexpr float LOG2E = 1.4426950408889634f;
    constexpr float LN2   = 0.6931471805599453f;
    const int b = blockIdx.x;
    const int lane = threadIdx.x;
    const int len = lengths[b];
    const bool act = lane < KK;
    const int li = act ? lane : 0;

    __shared__ __align__(16) float Ul[KK];

    const float* fb = feats + (size_t)b*TT*NST;
    float a2 = fb[li*KK + START_TAG] * LOG2E;
    float c0 = __uint_as_float(__builtin_amdgcn_readfirstlane(__float_as_uint(a2)));
    float CW = c0;
    float wk = act ? fexp2(a2 - c0) : 0.f;

    const int nseg = (len - 1 + SEGL - 1) / SEGL;

    if (act && nseg > 0){
        float4 mA[5], mB[5];
        int cA = 0, cB = 0;
        auto LDM = [&](int s2, float4 (&m)[5], int& c){
            const float* base = wseg + (size_t)(b*SEGS + s2)*SEGSTRIDE;
            const float4* p4 = (const float4*)(base + li*KK);
            m[0]=p4[0]; m[1]=p4[1]; m[2]=p4[2]; m[3]=p4[3]; m[4]=p4[4];
            c = ((const int*)base)[NST + li];
        };
        auto STEP = [&](float4 (&m)[5], int c){
            int e = (int)((__float_as_uint(wk) >> 23) & 255) - 127;
            int q = __builtin_amdgcn_readfirstlane(c + e);   // approx-max exponent (validated R4)
            Ul[li] = ldexpf(wk, c - q);
            asm volatile("s_waitcnt lgkmcnt(0)" ::: "memory");
            const float4* up = (const float4*)Ul;
            float4 u0 = up[0], u1 = up[1], u2 = up[2], u3 = up[3], u4 = up[4];
            float s0 = m[0].x*u0.x, s1 = m[0].y*u0.y;
            s0 = fmaf(m[0].z,u0.z,s0); s1 = fmaf(m[0].w,u0.w,s1);
            s0 = fmaf(m[1].x,u1.x,s0); s1 = fmaf(m[1].y,u1.y,s1);
            s0 = fmaf(m[1].z,u1.z,s0); s1 = fmaf(m[1].w,u1.w,s1);
            s0 = fmaf(m[2].x,u2.x,s0); s1 = fmaf(m[2].y,u2.y,s1);
            s0 = fmaf(m[2].z,u2.z,s0); s1 = fmaf(m[2].w,u2.w,s1);
            s0 = fmaf(m[3].x,u3.x,s0); s1 = fmaf(m[3].y,u3.y,s1);
            s0 = fmaf(m[3].z,u3.z,s0); s1 = fmaf(m[3].w,u3.w,s1);
            s0 = fmaf(m[4].x,u4.x,s0); s1 = fmaf(m[4].y,u4.y,s1);
            s0 = fmaf(m[4].z,u4.z,s0); s1 = fmaf(m[4].w,u4.w,s1);
            wk = s0 + s1;
            CW += (float)q;
            asm volatile("s_waitcnt lgkmcnt(0)" ::: "memory"); // Ul reads done before next write
        };
        LDM(0, mA, cA);
        for (int s2 = 0; s2 < nseg; ){
            if (s2 + 1 < nseg) LDM(s2 + 1, mB, cB);
            STEP(mA, cA);
            ++s2; if (s2 >= nseg) break;
            if (s2 + 1 < nseg) LDM(s2 + 1, mA, cA);
            STEP(mB, cB);
            ++s2;
        }
    }

    float term = act ? wk * fexp2(trans[STOP_TAG*KK + li] * LOG2E) : 0.f;
    #pragma unroll
    for (int o = 32; o > 0; o >>= 1) term += __shfl_xor(term, o, 64);
    if (lane == 0){
        float lse = LN2 * (CW + flog2(term));
        int last = targets[b*TT + len - 1];
        partialA[b] = lse - trans[STOP_TAG*KK + last];
    }
}

// ============ fallback: proven R1 serial forward ============
__global__ __launch_bounds__(64,1) void fwd_serial(
    const float* __restrict__ feats, const float* __restrict__ trans,
    const int* __restrict__ targets, const int* __restrict__ lengths,
    float* __restrict__ partialA)
{
    constexpr float LOG2E = 1.4426950408889634f;
    constexpr float LN2   = 0.6931471805599453f;
    const int b    = blockIdx.x;
    const int lane = threadIdx.x;
    const int len  = lengths[b];
    const float* fb = feats + (size_t)b * TT * NST;
    __shared__ __align__(16) float alpha[KK];
    __shared__ __align__(16) float xs[KK];
    const bool act = lane < KK;
    const int  li  = act ? lane : 0;
    if (act) alpha[lane] = fb[lane * KK + START_TAG] * LOG2E;
    __syncthreads();
    float4 b0[5], b1[5], b2[5], b3[5];
    auto LOAD = [&](float4* dst, int t){
        int tc = (t < len) ? t : (len - 1);
        const float4* p = (const float4*)(fb + (size_t)tc * NST + li * KK);
        dst[0]=p[0]; dst[1]=p[1]; dst[2]=p[2]; dst[3]=p[3]; dst[4]=p[4];
    };
    auto STEP = [&](const float4* bufv){
        const float4* ap = (const float4*)alpha;
        float a[KK];
        #pragma unroll
        for (int q = 0; q < 5; ++q){
            float4 av = ap[q];
            a[4*q+0]=av.x; a[4*q+1]=av.y; a[4*q+2]=av.z; a[4*q+3]=av.w;
        }
        float v[KK];
        #pragma unroll
        for (int q = 0; q < 5; ++q){
            v[4*q+0] = bufv[q].x * LOG2E + a[4*q+0];
            v[4*q+1] = bufv[q].y * LOG2E + a[4*q+1];
            v[4*q+2] = bufv[q].z * LOG2E + a[4*q+2];
            v[4*q+3] = bufv[q].w * LOG2E + a[4*q+3];
        }
        float m = v[0];
        #pragma unroll
        for (int j = 1; j < KK; ++j) m = fmaxf(m, v[j]);
        float s = 0.f;
        #pragma unroll
        for (int j = 0; j < KK; ++j) s += fexp2(v[j] - m);
        float na = m + flog2(s);
        __syncthreads();
        if (act) alpha[lane] = na;
        __syncthreads();
    };
    LOAD(b0,1); LOAD(b1,2); LOAD(b2,3); LOAD(b3,4);
    int t = 1;
    while (t < len){
        STEP(b0); LOAD(b0, t+4); ++t; if (t >= len) break;
        STEP(b1); LOAD(b1, t+4); ++t; if (t >= len) break;
        STEP(b2); LOAD(b2, t+4); ++t; if (t >= len) break;
        STEP(b3); LOAD(b3, t+4); ++t;
    }
    if (act) xs[lane] = alpha[lane] + trans[STOP_TAG*KK + lane] * LOG2E;
    __syncthreads();
    if (lane == 0){
        float m = xs[0];
        for (int j = 1; j < KK; ++j) m = fmaxf(m, xs[j]);
        float s = 0.f;
        for (int j = 0; j < KK; ++j) s += fexp2(xs[j] - m);
        float lse = LN2 * (m + flog2(s));
        int last_tag = targets[b*TT + (len-1)];
        partialA[b] = lse - trans[STOP_TAG*KK + last_tag];
    }
}

// ============ gold path + final reduce (proven) ============
__global__ __launch_bounds__(256) void gold_kernel(
    const float* __restrict__ feats, const int* __restrict__ targets,
    const int* __restrict__ lengths, float* __restrict__ partialG)
{
    const int b   = blockIdx.x;
    const int tt  = blockIdx.y * 256 + threadIdx.x;
    const int len = lengths[b];
    float val = 0.f;
    if (tt < len){
        int tgt  = targets[b*TT + tt];
        int prev = (tt > 0) ? targets[b*TT + tt - 1] : START_TAG;
        val = feats[((size_t)b*TT + tt)*NST + tgt*KK + prev];
    }
    #pragma unroll
    for (int off = 32; off > 0; off >>= 1) val += __shfl_down(val, off);
    __shared__ float wsum[4];
    if ((threadIdx.x & 63) == 0) wsum[threadIdx.x >> 6] = val;
    __syncthreads();
    if (threadIdx.x == 0)
        partialG[b*gridDim.y + blockIdx.y] = wsum[0]+wsum[1]+wsum[2]+wsum[3];
}

__global__ __launch_bounds__(256) void final_kernel(
    const float* __restrict__ partialA, const float* __restrict__ partialG,
    float* __restrict__ out)
{
    int tid = threadIdx.x;
    float v = partialA[tid] - partialG[tid] - partialG[tid + 256];
    #pragma unroll
    for (int off = 32; off > 0; off >>= 1) v += __shfl_down(v, off);
    __shared__ float wsum[4];
    if ((tid & 63) == 0) wsum[tid >> 6] = v;
    __syncthreads();
    if (tid == 0) out[0] = wsum[0]+wsum[1]+wsum[2]+wsum[3];
}

extern "C" void kernel_launch(void* const* d_in, const int* in_sizes, int n_in,
                              void* d_out, int out_size, void* d_ws, size_t ws_size,
                              hipStream_t stream) {
    const float* feats   = (const float*)d_in[0];
    const float* trans   = (const float*)d_in[1];
    const int*   targets = (const int*)d_in[2];
    const int*   lengths = (const int*)d_in[3];

    float* ws       = (float*)d_ws;
    float* partialA = ws;          // 256 floats
    float* partialG = ws + 256;    // 512 floats
    float* wseg     = ws + WS_SEG_OFF;

    const size_t need4  = (size_t)(WS_SEG_OFF + (size_t)BB*128*SEGSTRIDE) * sizeof(float);
    const size_t need8  = (size_t)(WS_SEG_OFF + (size_t)BB*64*SEGSTRIDE) * sizeof(float);
    const size_t need16 = (size_t)(WS_SEG_OFF + (size_t)BB*32*SEGSTRIDE) * sizeof(float);

    if (ws_size >= need4){
        seg_kernel2<4,128><<<dim3((BB*128 + TPW-1)/TPW), dim3(64), 0, stream>>>(feats, lengths, wseg);
        chain_kernel2<4,128><<<dim3(BB), dim3(64), 0, stream>>>(feats, trans, targets, lengths, wseg, partialA);
    } else if (ws_size >= need8){
        seg_kernel2<8,64><<<dim3((BB*64 + TPW-1)/TPW), dim3(64), 0, stream>>>(feats, lengths, wseg);
        chain_kernel2<8,64><<<dim3(BB), dim3(64), 0, stream>>>(feats, trans, targets, lengths, wseg, partialA);
    } else if (ws_size >= need16){
        seg_kernel2<16,32><<<dim3((BB*32 + TPW-1)/TPW), dim3(64), 0, stream>>>(feats, lengths, wseg);
        chain_kernel2<16,32><<<dim3(BB), dim3(64), 0, stream>>>(feats, trans, targets, lengths, wseg, partialA);
    } else {
        fwd_serial<<<dim3(BB), dim3(64), 0, stream>>>(feats, trans, targets, lengths, partialA);
    }
    gold_kernel<<<dim3(BB, 2), dim3(256), 0, stream>>>(feats, targets, lengths, partialG);
    final_kernel<<<dim3(1), dim3(256), 0, stream>>>(partialA, partialG, (float*)d_out);
}

// Round 6
// 80.610 us; speedup vs baseline: 4.3043x; 4.3043x over previous
//
#include <hip/hip_runtime.h>
#include <math.h>
#include <stdint.h>

#define BB 256
#define TT 512
#define KK 20
#define START_TAG 18
#define STOP_TAG 19
#define NST 400
#define SEGSTRIDE 420        // 400 M + 20 col-exponents
#define WS_SEG_OFF 1024

__device__ __forceinline__ float fexp2(float x){ float r; asm("v_exp_f32 %0, %1":"=v"(r):"v"(x)); return r; }
__device__ __forceinline__ float flog2(float x){ float r; asm("v_log_f32 %0, %1":"=v"(r):"v"(x)); return r; }

// ============ pass 1: per-segment 20x20 matrix products ============
// 6 tasks/wave, 10 lanes/task, lane owns 2 COLUMNS of the running product.
// Staging (R3-proven): coalesced global loads -> regs -> exp2 -> ds_write;
// E-reads are same-address broadcasts within a task, task stride 404 floats
// (bank-disjoint across the 6 tasks). Depth-1 register prefetch hides HBM
// under the 20-row mat-vec. Per-column exact-pow2 renorm every 4 steps.
template<int SEGL, int SEGS>
__global__ __launch_bounds__(64,2) void seg_kernel3(
    const float* __restrict__ feats, const int* __restrict__ lengths,
    float* __restrict__ wseg)
{
    constexpr int TASKS2 = BB*SEGS;
    constexpr float LOG2E = 1.4426950408889634f;
    const int lane = threadIdx.x;

    __shared__ __align__(16) float E[6*404];   // 9696 B

    const bool alive = lane < 60;
    const int gc = alive ? (lane/10) : 5;
    const int c  = alive ? (lane%10) : (lane-60);   // 60-63 duplicate task 5, c 0..3
    int traw = blockIdx.x*6 + gc;
    const bool real = alive && (traw < TASKS2);
    const int task = (traw < TASKS2) ? traw : (TASKS2-1);
    const int b = task / SEGS;
    const int s = task - b*SEGS;
    const int seg0 = 1 + SEGL*s;
    const int len = lengths[b];
    int nv_ = len - seg0; nv_ = nv_ < 0 ? 0 : (nv_ > SEGL ? SEGL : nv_);

    int itmax = nv_;
    #pragma unroll
    for (int o = 32; o > 0; o >>= 1){ int t2 = __shfl_xor(itmax, o, 64); itmax = t2 > itmax ? t2 : itmax; }
    if (itmax == 0) return;

    // global row pointer: float offset 40*q + 4*c within the 400-float t-row
    const float* fb = feats + (size_t)b*TT*NST;
    int trow = seg0;
    const float* rp = fb + (size_t)trow*NST + 4*c;

    float4 fRaw[10];
    auto GLOAD = [&](){
        #pragma unroll
        for (int q = 0; q < 10; ++q) fRaw[q] = *(const float4*)(rp + 40*q);
        if (trow < TT-1){ rp += NST; ++trow; }
    };

    float* wb = &E[gc*404 + 4*c];
    const float* eb = &E[gc*404];

    float vA[20][2], vB[20][2];
    int cexp[2] = {0,0};
    #pragma unroll
    for (int j = 0; j < 20; ++j){
        vA[j][0] = (j == 2*c+0) ? 1.f : 0.f;
        vA[j][1] = (j == 2*c+1) ? 1.f : 0.f;
    }

    auto STEP = [&](float (&VIN)[20][2], float (&VOUT)[20][2], int it){
        asm volatile("s_waitcnt vmcnt(0)" ::: "memory");     // fRaw for step `it` landed
        #pragma unroll
        for (int q = 0; q < 10; ++q){
            float4 x = fRaw[q];
            x.x = fexp2(x.x*LOG2E); x.y = fexp2(x.y*LOG2E);
            x.z = fexp2(x.z*LOG2E); x.w = fexp2(x.w*LOG2E);
            *(float4*)(wb + 40*q) = x;
        }
        asm volatile("s_waitcnt lgkmcnt(0)" ::: "memory");   // wave's E writes complete
        if (it + 1 < itmax) GLOAD();                          // prefetch next row (regs, vmcnt)
        #pragma unroll
        for (int ii = 0; ii < 20; ++ii){
            float4 e0 = *(const float4*)(eb + ii*20 + 0);
            float4 e1 = *(const float4*)(eb + ii*20 + 4);
            float4 e2 = *(const float4*)(eb + ii*20 + 8);
            float4 e3 = *(const float4*)(eb + ii*20 + 12);
            float4 e4 = *(const float4*)(eb + ii*20 + 16);
            #pragma unroll
            for (int cc = 0; cc < 2; ++cc){
                float s0 = e0.x*VIN[0][cc];
                float s1 = e0.y*VIN[1][cc];
                s0 = fmaf(e0.z, VIN[2][cc],  s0);  s1 = fmaf(e0.w, VIN[3][cc],  s1);
                s0 = fmaf(e1.x, VIN[4][cc],  s0);  s1 = fmaf(e1.y, VIN[5][cc],  s1);
                s0 = fmaf(e1.z, VIN[6][cc],  s0);  s1 = fmaf(e1.w, VIN[7][cc],  s1);
                s0 = fmaf(e2.x, VIN[8][cc],  s0);  s1 = fmaf(e2.y, VIN[9][cc],  s1);
                s0 = fmaf(e2.z, VIN[10][cc], s0);  s1 = fmaf(e2.w, VIN[11][cc], s1);
                s0 = fmaf(e3.x, VIN[12][cc], s0);  s1 = fmaf(e3.y, VIN[13][cc], s1);
                s0 = fmaf(e3.z, VIN[14][cc], s0);  s1 = fmaf(e3.w, VIN[15][cc], s1);
                s0 = fmaf(e4.x, VIN[16][cc], s0);  s1 = fmaf(e4.y, VIN[17][cc], s1);
                s0 = fmaf(e4.z, VIN[18][cc], s0);  s1 = fmaf(e4.w, VIN[19][cc], s1);
                VOUT[ii][cc] = s0 + s1;
            }
        }
        const bool ok = (it < nv_);                          // freeze finished tasks
        #pragma unroll
        for (int j = 0; j < 20; ++j){
            VOUT[j][0] = ok ? VOUT[j][0] : VIN[j][0];
            VOUT[j][1] = ok ? VOUT[j][1] : VIN[j][1];
        }
        if ((it & 3) == 3){                                  // exact pow2 renorm per column
            #pragma unroll
            for (int cc = 0; cc < 2; ++cc){
                float mx = VOUT[0][cc];
                #pragma unroll
                for (int j = 1; j < 20; ++j) mx = fmaxf(mx, VOUT[j][cc]);
                int e = (int)((__float_as_uint(mx) >> 23) & 255) - 127;
                float sc = __uint_as_float((uint32_t)(127 - e) << 23);
                #pragma unroll
                for (int j = 0; j < 20; ++j) VOUT[j][cc] *= sc;
                cexp[cc] += e;
            }
        }
        asm volatile("s_waitcnt lgkmcnt(0)" ::: "memory");   // E reads retired before next overwrite
    };

    GLOAD();   // row for it=0
    int it = 0;
    while (true){
        STEP(vA, vB, it); ++it;
        if (it >= itmax){
            #pragma unroll
            for (int j = 0; j < 20; ++j){ vA[j][0] = vB[j][0]; vA[j][1] = vB[j][1]; }
            break;
        }
        STEP(vB, vA, it); ++it;
        if (it >= itmax) break;
    }

    if (real && nv_ > 0){
        float* out = wseg + (size_t)task * SEGSTRIDE;
        #pragma unroll
        for (int ii = 0; ii < 20; ++ii)
            *(float2*)&out[ii*20 + 2*c] = make_float2(vA[ii][0], vA[ii][1]);
        int* oi = (int*)out;
        oi[NST + 2*c + 0] = cexp[0];
        oi[NST + 2*c + 1] = cexp[1];
    }
}

// ============ pass 2: serial segment applications (<=SEGS steps) ============
template<int SEGL, int SEGS>
__global__ __launch_bounds__(64,1) void chain_kernel2(
    const float* __restrict__ feats, const float* __restrict__ trans,
    const int* __restrict__ targets, const int* __restrict__ lengths,
    const float* __restrict__ wseg, float* __restrict__ partialA)
{
    constexpr float LOG2E = 1.4426950408889634f;
    constexpr float LN2   = 0.6931471805599453f;
    const int b = blockIdx.x;
    const int lane = threadIdx.x;
    const int len = lengths[b];
    const bool act = lane < KK;
    const int li = act ? lane : 0;

    __shared__ __align__(16) float Ul[KK];

    const float* fb = feats + (size_t)b*TT*NST;
    float a2 = fb[li*KK + START_TAG] * LOG2E;
    float c0 = __uint_as_float(__builtin_amdgcn_readfirstlane(__float_as_uint(a2)));
    float CW = c0;
    float wk = act ? fexp2(a2 - c0) : 0.f;

    const int nseg = (len - 1 + SEGL - 1) / SEGL;

    if (act && nseg > 0){
        float4 mA[5], mB[5];
        int cA = 0, cB = 0;
        auto LDM = [&](int s2, float4 (&m)[5], int& c){
            const float* base = wseg + (size_t)(b*SEGS + s2)*SEGSTRIDE;
            const float4* p4 = (const float4*)(base + li*KK);
            m[0]=p4[0]; m[1]=p4[1]; m[2]=p4[2]; m[3]=p4[3]; m[4]=p4[4];
            c = ((const int*)base)[NST + li];
        };
        auto STEP = [&](float4 (&m)[5], int c){
            int e = (int)((__float_as_uint(wk) >> 23) & 255) - 127;
            int q = __builtin_amdgcn_readfirstlane(c + e);   // approx-max exponent (validated R4)
            Ul[li] = ldexpf(wk, c - q);
            asm volatile("s_waitcnt lgkmcnt(0)" ::: "memory");
            const float4* up = (const float4*)Ul;
            float4 u0 = up[0], u1 = up[1], u2 = up[2], u3 = up[3], u4 = up[4];
            float s0 = m[0].x*u0.x, s1 = m[0].y*u0.y;
            s0 = fmaf(m[0].z,u0.z,s0); s1 = fmaf(m[0].w,u0.w,s1);
            s0 = fmaf(m[1].x,u1.x,s0); s1 = fmaf(m[1].y,u1.y,s1);
            s0 = fmaf(m[1].z,u1.z,s0); s1 = fmaf(m[1].w,u1.w,s1);
            s0 = fmaf(m[2].x,u2.x,s0); s1 = fmaf(m[2].y,u2.y,s1);
            s0 = fmaf(m[2].z,u2.z,s0); s1 = fmaf(m[2].w,u2.w,s1);
            s0 = fmaf(m[3].x,u3.x,s0); s1 = fmaf(m[3].y,u3.y,s1);
            s0 = fmaf(m[3].z,u3.z,s0); s1 = fmaf(m[3].w,u3.w,s1);
            s0 = fmaf(m[4].x,u4.x,s0); s1 = fmaf(m[4].y,u4.y,s1);
            s0 = fmaf(m[4].z,u4.z,s0); s1 = fmaf(m[4].w,u4.w,s1);
            wk = s0 + s1;
            CW += (float)q;
            asm volatile("s_waitcnt lgkmcnt(0)" ::: "memory"); // Ul reads done before next write
        };
        LDM(0, mA, cA);
        for (int s2 = 0; s2 < nseg; ){
            if (s2 + 1 < nseg) LDM(s2 + 1, mB, cB);
            STEP(mA, cA);
            ++s2; if (s2 >= nseg) break;
            if (s2 + 1 < nseg) LDM(s2 + 1, mA, cA);
            STEP(mB, cB);
            ++s2;
        }
    }

    float term = act ? wk * fexp2(trans[STOP_TAG*KK + li] * LOG2E) : 0.f;
    #pragma unroll
    for (int o = 32; o > 0; o >>= 1) term += __shfl_xor(term, o, 64);
    if (lane == 0){
        float lse = LN2 * (CW + flog2(term));
        int last = targets[b*TT + len - 1];
        partialA[b] = lse - trans[STOP_TAG*KK + last];
    }
}

// ============ fallback: proven R1 serial forward ============
__global__ __launch_bounds__(64,1) void fwd_serial(
    const float* __restrict__ feats, const float* __restrict__ trans,
    const int* __restrict__ targets, const int* __restrict__ lengths,
    float* __restrict__ partialA)
{
    constexpr float LOG2E = 1.4426950408889634f;
    constexpr float LN2   = 0.6931471805599453f;
    const int b    = blockIdx.x;
    const int lane = threadIdx.x;
    const int len  = lengths[b];
    const float* fb = feats + (size_t)b * TT * NST;
    __shared__ __align__(16) float alpha[KK];
    __shared__ __align__(16) float xs[KK];
    const bool act = lane < KK;
    const int  li  = act ? lane : 0;
    if (act) alpha[lane] = fb[lane * KK + START_TAG] * LOG2E;
    __syncthreads();
    float4 b0[5], b1[5], b2[5], b3[5];
    auto LOAD = [&](float4* dst, int t){
        int tc = (t < len) ? t : (len - 1);
        const float4* p = (const float4*)(fb + (size_t)tc * NST + li * KK);
        dst[0]=p[0]; dst[1]=p[1]; dst[2]=p[2]; dst[3]=p[3]; dst[4]=p[4];
    };
    auto STEP = [&](const float4* bufv){
        const float4* ap = (const float4*)alpha;
        float a[KK];
        #pragma unroll
        for (int q = 0; q < 5; ++q){
            float4 av = ap[q];
            a[4*q+0]=av.x; a[4*q+1]=av.y; a[4*q+2]=av.z; a[4*q+3]=av.w;
        }
        float v[KK];
        #pragma unroll
        for (int q = 0; q < 5; ++q){
            v[4*q+0] = bufv[q].x * LOG2E + a[4*q+0];
            v[4*q+1] = bufv[q].y * LOG2E + a[4*q+1];
            v[4*q+2] = bufv[q].z * LOG2E + a[4*q+2];
            v[4*q+3] = bufv[q].w * LOG2E + a[4*q+3];
        }
        float m = v[0];
        #pragma unroll
        for (int j = 1; j < KK; ++j) m = fmaxf(m, v[j]);
        float s = 0.f;
        #pragma unroll
        for (int j = 0; j < KK; ++j) s += fexp2(v[j] - m);
        float na = m + flog2(s);
        __syncthreads();
        if (act) alpha[lane] = na;
        __syncthreads();
    };
    LOAD(b0,1); LOAD(b1,2); LOAD(b2,3); LOAD(b3,4);
    int t = 1;
    while (t < len){
        STEP(b0); LOAD(b0, t+4); ++t; if (t >= len) break;
        STEP(b1); LOAD(b1, t+4); ++t; if (t >= len) break;
        STEP(b2); LOAD(b2, t+4); ++t; if (t >= len) break;
        STEP(b3); LOAD(b3, t+4); ++t;
    }
    if (act) xs[lane] = alpha[lane] + trans[STOP_TAG*KK + lane] * LOG2E;
    __syncthreads();
    if (lane == 0){
        float m = xs[0];
        for (int j = 1; j < KK; ++j) m = fmaxf(m, xs[j]);
        float s = 0.f;
        for (int j = 0; j < KK; ++j) s += fexp2(xs[j] - m);
        float lse = LN2 * (m + flog2(s));
        int last_tag = targets[b*TT + (len-1)];
        partialA[b] = lse - trans[STOP_TAG*KK + last_tag];
    }
}

// ============ gold path + final reduce (proven) ============
__global__ __launch_bounds__(256) void gold_kernel(
    const float* __restrict__ feats, const int* __restrict__ targets,
    const int* __restrict__ lengths, float* __restrict__ partialG)
{
    const int b   = blockIdx.x;
    const int tt  = blockIdx.y * 256 + threadIdx.x;
    const int len = lengths[b];
    float val = 0.f;
    if (tt < len){
        int tgt  = targets[b*TT + tt];
        int prev = (tt > 0) ? targets[b*TT + tt - 1] : START_TAG;
        val = feats[((size_t)b*TT + tt)*NST + tgt*KK + prev];
    }
    #pragma unroll
    for (int off = 32; off > 0; off >>= 1) val += __shfl_down(val, off);
    __shared__ float wsum[4];
    if ((threadIdx.x & 63) == 0) wsum[threadIdx.x >> 6] = val;
    __syncthreads();
    if (threadIdx.x == 0)
        partialG[b*gridDim.y + blockIdx.y] = wsum[0]+wsum[1]+wsum[2]+wsum[3];
}

__global__ __launch_bounds__(256) void final_kernel(
    const float* __restrict__ partialA, const float* __restrict__ partialG,
    float* __restrict__ out)
{
    int tid = threadIdx.x;
    float v = partialA[tid] - partialG[tid] - partialG[tid + 256];
    #pragma unroll
    for (int off = 32; off > 0; off >>= 1) v += __shfl_down(v, off);
    __shared__ float wsum[4];
    if ((tid & 63) == 0) wsum[tid >> 6] = v;
    __syncthreads();
    if (tid == 0) out[0] = wsum[0]+wsum[1]+wsum[2]+wsum[3];
}

extern "C" void kernel_launch(void* const* d_in, const int* in_sizes, int n_in,
                              void* d_out, int out_size, void* d_ws, size_t ws_size,
                              hipStream_t stream) {
    const float* feats   = (const float*)d_in[0];
    const float* trans   = (const float*)d_in[1];
    const int*   targets = (const int*)d_in[2];
    const int*   lengths = (const int*)d_in[3];

    float* ws       = (float*)d_ws;
    float* partialA = ws;          // 256 floats
    float* partialG = ws + 256;    // 512 floats
    float* wseg     = ws + WS_SEG_OFF;

    const size_t need8  = (size_t)(WS_SEG_OFF + (size_t)BB*64*SEGSTRIDE) * sizeof(float);
    const size_t need16 = (size_t)(WS_SEG_OFF + (size_t)BB*32*SEGSTRIDE) * sizeof(float);

    if (ws_size >= need8){
        seg_kernel3<8,64><<<dim3((BB*64 + 5)/6), dim3(64), 0, stream>>>(feats, lengths, wseg);
        chain_kernel2<8,64><<<dim3(BB), dim3(64), 0, stream>>>(feats, trans, targets, lengths, wseg, partialA);
    } else if (ws_size >= need16){
        seg_kernel3<16,32><<<dim3((BB*32 + 5)/6), dim3(64), 0, stream>>>(feats, lengths, wseg);
        chain_kernel2<16,32><<<dim3(BB), dim3(64), 0, stream>>>(feats, trans, targets, lengths, wseg, partialA);
    } else {
        fwd_serial<<<dim3(BB), dim3(64), 0, stream>>>(feats, trans, targets, lengths, partialA);
    }
    gold_kernel<<<dim3(BB, 2), dim3(256), 0, stream>>>(feats, targets, lengths, partialG);
    final_kernel<<<dim3(1), dim3(256), 0, stream>>>(partialA, partialG, (float*)d_out);
}

// Round 7
// 52.416 us; speedup vs baseline: 6.6196x; 1.5379x over previous
//
#include <hip/hip_runtime.h>
#include <math.h>
#include <stdint.h>

#define BB 256
#define TT 512
#define KK 20
#define START_TAG 18
#define STOP_TAG 19
#define NST 400
#define SEGSTRIDE 420        // 400 M + 20 col-exponents
#define WS_SEG_OFF 1024

typedef __bf16 bf16x8 __attribute__((ext_vector_type(8)));
typedef float f32x16 __attribute__((ext_vector_type(16)));
typedef uint32_t u32x4 __attribute__((ext_vector_type(4)));

__device__ __forceinline__ float fexp2(float x){ float r; asm("v_exp_f32 %0, %1":"=v"(r):"v"(x)); return r; }
__device__ __forceinline__ float flog2(float x){ float r; asm("v_log_f32 %0, %1":"=v"(r):"v"(x)); return r; }
__device__ __forceinline__ uint32_t pk_bf16(float lo, float hi){
  uint32_t r; asm("v_cvt_pk_bf16_f32 %0, %1, %2":"=v"(r):"v"(lo),"v"(hi)); return r;
}
__device__ __forceinline__ void pswap(uint32_t &a, uint32_t &b){
  asm("v_permlane32_swap_b32 %0, %1":"+v"(a),"+v"(b));
}
__device__ __forceinline__ f32x16 mfma_bf16(u32x4 a, u32x4 b, f32x16 c){
  return __builtin_amdgcn_mfma_f32_32x32x16_bf16(
    __builtin_bit_cast(bf16x8,a), __builtin_bit_cast(bf16x8,b), c, 0,0,0);
}

// ============ pass 1: per-segment 20x20 matrix products via MFMA ============
// ONE task per wave. V kept as MFMA B-operand (bf16), E staged straight from
// global into A-operand registers (exp2 + cvt_pk, no LDS at all).
// Per step: acc = E_t (32x32 padded) x V ; C->B via cvt_pk + permlane32_swap
// (C/D layout col=lane&31,row=(reg&3)+8(reg>>2)+4hi: row-halves live in lane
// and lane^32 -> one swap per reg-pair rebuilds the K-major B fragment).
// Exact pow2 renorm per column at segment end (+ mid at it==7 for SEGL=16).
template<int SEGL, int SEGS>
__global__ __launch_bounds__(64) void seg_mfma(
    const float* __restrict__ feats, const int* __restrict__ lengths,
    float* __restrict__ wseg)
{
  constexpr float LOG2E = 1.4426950408889634f;
  const int lane = threadIdx.x;
  const int n  = lane & 31;    // A-row / B-col / C-col
  const int hi = lane >> 5;    // k-block selector
  const int task = blockIdx.x;
  const int b = task / SEGS;
  const int s = task - b*SEGS;
  const int seg0 = 1 + SEGL*s;
  const int len = lengths[b];
  int nv = len - seg0; nv = nv < 0 ? 0 : (nv > SEGL ? SEGL : nv);
  if (nv <= 0) return;                         // wave-uniform

  const bool rowok = n < KK;
  const int rli = rowok ? n : 0;               // clamp addr, zero later
  const float* rbase = feats + (size_t)(b*TT + seg0)*NST + rli*KK;
  const int off0 = hi ? 8 : 0;

  // ---- identity B (bf16), pad zero ----
  u32x4 B0, B1;
  #pragma unroll
  for (int d=0; d<4; ++d){
    int k0 = hi*8 + 2*d;
    uint32_t v = 0;
    if (k0   == n && n < KK) v |= 0x3F80u;
    if (k0+1 == n && n < KK) v |= 0x3F800000u;
    B0[d] = v;
    int m0 = 16 + hi*8 + 2*d;
    uint32_t u = 0;
    if (m0   == n && n < KK) u |= 0x3F80u;
    if (m0+1 == n && n < KK) u |= 0x3F800000u;
    B1[d] = u;
  }

  int cexp = 0;
  f32x16 acc;
  #pragma unroll
  for (int r=0;r<16;++r) acc[r] = 0.f;

  float4 a0,a1,a2, p0,p1,p2;
  auto LD = [&](int it, float4 &r0, float4 &r1, float4 &r2){
    const float* p = rbase + (size_t)it*NST;
    r0 = *(const float4*)(p + off0);
    r1 = *(const float4*)(p + off0 + 4);
    r2 = (hi == 0) ? *(const float4*)(p + 16) : make_float4(0.f,0.f,0.f,0.f);
  };
  auto CONV = [&](const float4 &r0, const float4 &r1, const float4 &r2,
                  u32x4 &A0, u32x4 &A1){
    uint32_t w0 = pk_bf16(fexp2(r0.x*LOG2E), fexp2(r0.y*LOG2E));
    uint32_t w1 = pk_bf16(fexp2(r0.z*LOG2E), fexp2(r0.w*LOG2E));
    uint32_t w2 = pk_bf16(fexp2(r1.x*LOG2E), fexp2(r1.y*LOG2E));
    uint32_t w3 = pk_bf16(fexp2(r1.z*LOG2E), fexp2(r1.w*LOG2E));
    uint32_t w4 = pk_bf16(fexp2(r2.x*LOG2E), fexp2(r2.y*LOG2E));
    uint32_t w5 = pk_bf16(fexp2(r2.z*LOG2E), fexp2(r2.w*LOG2E));
    if (!rowok){ w0=0u; w1=0u; w2=0u; w3=0u; }
    if (!(rowok && hi==0)){ w4=0u; w5=0u; }
    A0[0]=w0; A0[1]=w1; A0[2]=w2; A0[3]=w3;
    A1[0]=w4; A1[1]=w5; A1[2]=0u; A1[3]=0u;
  };
  auto RENORM = [&](){
    float mx = acc[0];
    #pragma unroll
    for (int r=1;r<16;++r) mx = fmaxf(mx, acc[r]);
    mx = fmaxf(mx, __shfl_xor(mx, 32, 64));     // combine with partner rows
    int e = (int)((__float_as_uint(mx) >> 23) & 255) - 127;
    if (e < -100) e = -100;
    float sc = __uint_as_float((uint32_t)(127 - e) << 23);
    #pragma unroll
    for (int r=0;r<16;++r) acc[r] *= sc;
    cexp += e;
  };
  auto C2B = [&](){
    uint32_t x0 = pk_bf16(acc[0],  acc[1]);    // rows (0,1)+4hi
    uint32_t x1 = pk_bf16(acc[2],  acc[3]);    // rows (2,3)+4hi
    uint32_t x2 = pk_bf16(acc[4],  acc[5]);    // rows (8,9)+4hi
    uint32_t x3 = pk_bf16(acc[6],  acc[7]);    // rows (10,11)+4hi
    uint32_t x4 = pk_bf16(acc[8],  acc[9]);    // rows (16,17)+4hi
    uint32_t x5 = pk_bf16(acc[10], acc[11]);   // rows (18,19)+4hi
    uint32_t x6 = pk_bf16(acc[12], acc[13]);   // rows (24,25)+4hi
    uint32_t x7 = pk_bf16(acc[14], acc[15]);   // rows (26,27)+4hi
    pswap(x0,x2); pswap(x1,x3); pswap(x4,x6); pswap(x5,x7);
    B0[0]=x0; B0[1]=x1; B0[2]=x2; B0[3]=x3;    // k = hi*8 + 0..7
    B1[0]=x4; B1[1]=x5; B1[2]=x6; B1[3]=x7;    // k = 16 + hi*8 + 0..7
  };

  LD(0, a0,a1,a2);
  for (int it=0; it<nv-1; ++it){
    LD(it+1, p0,p1,p2);                        // prefetch next row
    u32x4 A0, A1; CONV(a0,a1,a2, A0,A1);
    f32x16 z;
    #pragma unroll
    for (int r=0;r<16;++r) z[r] = 0.f;
    acc = mfma_bf16(A0, B0, z);
    acc = mfma_bf16(A1, B1, acc);
    if (SEGL > 8 && (it & 7) == 7) RENORM();   // overflow guard for long segs
    C2B();
    a0=p0; a1=p1; a2=p2;
  }
  { // final step: keep fp32 acc, no C->B
    u32x4 A0, A1; CONV(a0,a1,a2, A0,A1);
    f32x16 z;
    #pragma unroll
    for (int r=0;r<16;++r) z[r] = 0.f;
    acc = mfma_bf16(A0, B0, z);
    acc = mfma_bf16(A1, B1, acc);
  }
  RENORM();

  float* out = wseg + (size_t)task*SEGSTRIDE;
  #pragma unroll
  for (int r=0;r<16;++r){
    int row = (r&3) + 8*(r>>2) + 4*hi;
    if (row < KK && n < KK) out[row*KK + n] = acc[r];
  }
  if (hi==0 && n<KK) ((int*)out)[NST + n] = cexp;
}

// ============ pass 2: serial segment applications (<=SEGS steps) ============
template<int SEGL, int SEGS>
__global__ __launch_bounds__(64,1) void chain_kernel2(
    const float* __restrict__ feats, const float* __restrict__ trans,
    const int* __restrict__ targets, const int* __restrict__ lengths,
    const float* __restrict__ wseg, float* __restrict__ partialA)
{
    constexpr float LOG2E = 1.4426950408889634f;
    constexpr float LN2   = 0.6931471805599453f;
    const int b = blockIdx.x;
    const int lane = threadIdx.x;
    const int len = lengths[b];
    const bool act = lane < KK;
    const int li = act ? lane : 0;

    __shared__ __align__(16) float Ul[KK];

    const float* fb = feats + (size_t)b*TT*NST;
    float a2 = fb[li*KK + START_TAG] * LOG2E;
    float c0 = __uint_as_float(__builtin_amdgcn_readfirstlane(__float_as_uint(a2)));
    float CW = c0;
    float wk = act ? fexp2(a2 - c0) : 0.f;

    const int nseg = (len - 1 + SEGL - 1) / SEGL;

    if (act && nseg > 0){
        float4 mA[5], mB[5];
        int cA = 0, cB = 0;
        auto LDM = [&](int s2, float4 (&m)[5], int& c){
            const float* base = wseg + (size_t)(b*SEGS + s2)*SEGSTRIDE;
            const float4* p4 = (const float4*)(base + li*KK);
            m[0]=p4[0]; m[1]=p4[1]; m[2]=p4[2]; m[3]=p4[3]; m[4]=p4[4];
            c = ((const int*)base)[NST + li];
        };
        auto STEP = [&](float4 (&m)[5], int c){
            int e = (int)((__float_as_uint(wk) >> 23) & 255) - 127;
            int q = __builtin_amdgcn_readfirstlane(c + e);   // approx-max exponent (validated R4)
            Ul[li] = ldexpf(wk, c - q);
            asm volatile("s_waitcnt lgkmcnt(0)" ::: "memory");
            const float4* up = (const float4*)Ul;
            float4 u0 = up[0], u1 = up[1], u2 = up[2], u3 = up[3], u4 = up[4];
            float s0 = m[0].x*u0.x, s1 = m[0].y*u0.y;
            s0 = fmaf(m[0].z,u0.z,s0); s1 = fmaf(m[0].w,u0.w,s1);
            s0 = fmaf(m[1].x,u1.x,s0); s1 = fmaf(m[1].y,u1.y,s1);
            s0 = fmaf(m[1].z,u1.z,s0); s1 = fmaf(m[1].w,u1.w,s1);
            s0 = fmaf(m[2].x,u2.x,s0); s1 = fmaf(m[2].y,u2.y,s1);
            s0 = fmaf(m[2].z,u2.z,s0); s1 = fmaf(m[2].w,u2.w,s1);
            s0 = fmaf(m[3].x,u3.x,s0); s1 = fmaf(m[3].y,u3.y,s1);
            s0 = fmaf(m[3].z,u3.z,s0); s1 = fmaf(m[3].w,u3.w,s1);
            s0 = fmaf(m[4].x,u4.x,s0); s1 = fmaf(m[4].y,u4.y,s1);
            s0 = fmaf(m[4].z,u4.z,s0); s1 = fmaf(m[4].w,u4.w,s1);
            wk = s0 + s1;
            CW += (float)q;
            asm volatile("s_waitcnt lgkmcnt(0)" ::: "memory"); // Ul reads done before next write
        };
        LDM(0, mA, cA);
        for (int s2 = 0; s2 < nseg; ){
            if (s2 + 1 < nseg) LDM(s2 + 1, mB, cB);
            STEP(mA, cA);
            ++s2; if (s2 >= nseg) break;
            if (s2 + 1 < nseg) LDM(s2 + 1, mA, cA);
            STEP(mB, cB);
            ++s2;
        }
    }

    float term = act ? wk * fexp2(trans[STOP_TAG*KK + li] * LOG2E) : 0.f;
    #pragma unroll
    for (int o = 32; o > 0; o >>= 1) term += __shfl_xor(term, o, 64);
    if (lane == 0){
        float lse = LN2 * (CW + flog2(term));
        int last = targets[b*TT + len - 1];
        partialA[b] = lse - trans[STOP_TAG*KK + last];
    }
}

// ============ fallback: proven R1 serial forward ============
__global__ __launch_bounds__(64,1) void fwd_serial(
    const float* __restrict__ feats, const float* __restrict__ trans,
    const int* __restrict__ targets, const int* __restrict__ lengths,
    float* __restrict__ partialA)
{
    constexpr float LOG2E = 1.4426950408889634f;
    constexpr float LN2   = 0.6931471805599453f;
    const int b    = blockIdx.x;
    const int lane = threadIdx.x;
    const int len  = lengths[b];
    const float* fb = feats + (size_t)b * TT * NST;
    __shared__ __align__(16) float alpha[KK];
    __shared__ __align__(16) float xs[KK];
    const bool act = lane < KK;
    const int  li  = act ? lane : 0;
    if (act) alpha[lane] = fb[lane * KK + START_TAG] * LOG2E;
    __syncthreads();
    float4 b0[5], b1[5], b2[5], b3[5];
    auto LOAD = [&](float4* dst, int t){
        int tc = (t < len) ? t : (len - 1);
        const float4* p = (const float4*)(fb + (size_t)tc * NST + li * KK);
        dst[0]=p[0]; dst[1]=p[1]; dst[2]=p[2]; dst[3]=p[3]; dst[4]=p[4];
    };
    auto STEP = [&](const float4* bufv){
        const float4* ap = (const float4*)alpha;
        float a[KK];
        #pragma unroll
        for (int q = 0; q < 5; ++q){
            float4 av = ap[q];
            a[4*q+0]=av.x; a[4*q+1]=av.y; a[4*q+2]=av.z; a[4*q+3]=av.w;
        }
        float v[KK];
        #pragma unroll
        for (int q = 0; q < 5; ++q){
            v[4*q+0] = bufv[q].x * LOG2E + a[4*q+0];
            v[4*q+1] = bufv[q].y * LOG2E + a[4*q+1];
            v[4*q+2] = bufv[q].z * LOG2E + a[4*q+2];
            v[4*q+3] = bufv[q].w * LOG2E + a[4*q+3];
        }
        float m = v[0];
        #pragma unroll
        for (int j = 1; j < KK; ++j) m = fmaxf(m, v[j]);
        float s = 0.f;
        #pragma unroll
        for (int j = 0; j < KK; ++j) s += fexp2(v[j] - m);
        float na = m + flog2(s);
        __syncthreads();
        if (act) alpha[lane] = na;
        __syncthreads();
    };
    LOAD(b0,1); LOAD(b1,2); LOAD(b2,3); LOAD(b3,4);
    int t = 1;
    while (t < len){
        STEP(b0); LOAD(b0, t+4); ++t; if (t >= len) break;
        STEP(b1); LOAD(b1, t+4); ++t; if (t >= len) break;
        STEP(b2); LOAD(b2, t+4); ++t; if (t >= len) break;
        STEP(b3); LOAD(b3, t+4); ++t;
    }
    if (act) xs[lane] = alpha[lane] + trans[STOP_TAG*KK + lane] * LOG2E;
    __syncthreads();
    if (lane == 0){
        float m = xs[0];
        for (int j = 1; j < KK; ++j) m = fmaxf(m, xs[j]);
        float s = 0.f;
        for (int j = 0; j < KK; ++j) s += fexp2(xs[j] - m);
        float lse = LN2 * (m + flog2(s));
        int last_tag = targets[b*TT + (len-1)];
        partialA[b] = lse - trans[STOP_TAG*KK + last_tag];
    }
}

// ============ gold path + final reduce (proven) ============
__global__ __launch_bounds__(256) void gold_kernel(
    const float* __restrict__ feats, const int* __restrict__ targets,
    const int* __restrict__ lengths, float* __restrict__ partialG)
{
    const int b   = blockIdx.x;
    const int tt  = blockIdx.y * 256 + threadIdx.x;
    const int len = lengths[b];
    float val = 0.f;
    if (tt < len){
        int tgt  = targets[b*TT + tt];
        int prev = (tt > 0) ? targets[b*TT + tt - 1] : START_TAG;
        val = feats[((size_t)b*TT + tt)*NST + tgt*KK + prev];
    }
    #pragma unroll
    for (int off = 32; off > 0; off >>= 1) val += __shfl_down(val, off);
    __shared__ float wsum[4];
    if ((threadIdx.x & 63) == 0) wsum[threadIdx.x >> 6] = val;
    __syncthreads();
    if (threadIdx.x == 0)
        partialG[b*gridDim.y + blockIdx.y] = wsum[0]+wsum[1]+wsum[2]+wsum[3];
}

__global__ __launch_bounds__(256) void final_kernel(
    const float* __restrict__ partialA, const float* __restrict__ partialG,
    float* __restrict__ out)
{
    int tid = threadIdx.x;
    float v = partialA[tid] - partialG[tid] - partialG[tid + 256];
    #pragma unroll
    for (int off = 32; off > 0; off >>= 1) v += __shfl_down(v, off);
    __shared__ float wsum[4];
    if ((tid & 63) == 0) wsum[tid >> 6] = v;
    __syncthreads();
    if (tid == 0) out[0] = wsum[0]+wsum[1]+wsum[2]+wsum[3];
}

extern "C" void kernel_launch(void* const* d_in, const int* in_sizes, int n_in,
                              void* d_out, int out_size, void* d_ws, size_t ws_size,
                              hipStream_t stream) {
    const float* feats   = (const float*)d_in[0];
    const float* trans   = (const float*)d_in[1];
    const int*   targets = (const int*)d_in[2];
    const int*   lengths = (const int*)d_in[3];

    float* ws       = (float*)d_ws;
    float* partialA = ws;          // 256 floats
    float* partialG = ws + 256;    // 512 floats
    float* wseg     = ws + WS_SEG_OFF;

    const size_t need8  = (size_t)(WS_SEG_OFF + (size_t)BB*64*SEGSTRIDE) * sizeof(float);
    const size_t need16 = (size_t)(WS_SEG_OFF + (size_t)BB*32*SEGSTRIDE) * sizeof(float);

    if (ws_size >= need8){
        seg_mfma<8,64><<<dim3(BB*64), dim3(64), 0, stream>>>(feats, lengths, wseg);
        chain_kernel2<8,64><<<dim3(BB), dim3(64), 0, stream>>>(feats, trans, targets, lengths, wseg, partialA);
    } else if (ws_size >= need16){
        seg_mfma<16,32><<<dim3(BB*32), dim3(64), 0, stream>>>(feats, lengths, wseg);
        chain_kernel2<16,32><<<dim3(BB), dim3(64), 0, stream>>>(feats, trans, targets, lengths, wseg, partialA);
    } else {
        fwd_serial<<<dim3(BB), dim3(64), 0, stream>>>(feats, trans, targets, lengths, partialA);
    }
    gold_kernel<<<dim3(BB, 2), dim3(256), 0, stream>>>(feats, targets, lengths, partialG);
    final_kernel<<<dim3(1), dim3(256), 0, stream>>>(partialA, partialG, (float*)d_out);
}

// Round 8
// 48.834 us; speedup vs baseline: 7.1050x; 1.0733x over previous
//
#include <hip/hip_runtime.h>
#include <math.h>
#include <stdint.h>

#define BB 256
#define TT 512
#define KK 20
#define START_TAG 18
#define STOP_TAG 19
#define NST 400
#define SEGSTRIDE 420        // 400 M + 20 col-exponents
#define WS_SEG_OFF 1024

typedef __bf16 bf16x8 __attribute__((ext_vector_type(8)));
typedef float f32x16 __attribute__((ext_vector_type(16)));
typedef uint32_t u32x4 __attribute__((ext_vector_type(4)));

__device__ __forceinline__ float fexp2(float x){ float r; asm("v_exp_f32 %0, %1":"=v"(r):"v"(x)); return r; }
__device__ __forceinline__ float flog2(float x){ float r; asm("v_log_f32 %0, %1":"=v"(r):"v"(x)); return r; }
__device__ __forceinline__ uint32_t pk_bf16(float lo, float hi){
  uint32_t r; asm("v_cvt_pk_bf16_f32 %0, %1, %2":"=v"(r):"v"(lo),"v"(hi)); return r;
}
__device__ __forceinline__ void pswap(uint32_t &a, uint32_t &b){
  asm("v_permlane32_swap_b32 %0, %1":"+v"(a),"+v"(b));
}
__device__ __forceinline__ f32x16 mfma_bf16(u32x4 a, u32x4 b, f32x16 c){
  return __builtin_amdgcn_mfma_f32_32x32x16_bf16(
    __builtin_bit_cast(bf16x8,a), __builtin_bit_cast(bf16x8,b), c, 0,0,0);
}

// ============ pass 1: per-segment 20x20 matrix products via MFMA ============
// ONE task (= 64 consecutive steps) per wave; 2048 waves = full co-residency.
// Per step: acc = E_t (32x32 padded) x V ; C->B via cvt_pk + permlane32_swap
// (C/D layout col=lane&31,row=(reg&3)+8(reg>>2)+4hi — verified R7).
// Depth-2 register prefetch of the next rows hides HBM latency.
// Exact per-column pow2 renorm every 8 steps + at segment end.
template<int SEGL, int SEGS>
__global__ __launch_bounds__(64) void seg_mfma(
    const float* __restrict__ feats, const int* __restrict__ lengths,
    float* __restrict__ wseg)
{
  constexpr float LOG2E = 1.4426950408889634f;
  const int lane = threadIdx.x;
  const int n  = lane & 31;    // A-row / B-col / C-col
  const int hi = lane >> 5;    // k-block selector
  const int task = blockIdx.x;
  const int b = task / SEGS;
  const int s = task - b*SEGS;
  const int seg0 = 1 + SEGL*s;
  const int len = lengths[b];
  int nv = len - seg0; nv = nv < 0 ? 0 : (nv > SEGL ? SEGL : nv);
  if (nv <= 0) return;                         // wave-uniform

  const bool rowok = n < KK;
  const int rli = rowok ? n : 0;               // clamp addr, zero later
  const float* rbase = feats + (size_t)(b*TT + seg0)*NST + rli*KK;
  const int off0 = hi ? 8 : 0;

  // ---- identity B (bf16), pad zero ----
  u32x4 B0, B1;
  #pragma unroll
  for (int d=0; d<4; ++d){
    int k0 = hi*8 + 2*d;
    uint32_t v = 0;
    if (k0   == n && n < KK) v |= 0x3F80u;
    if (k0+1 == n && n < KK) v |= 0x3F800000u;
    B0[d] = v;
    int m0 = 16 + hi*8 + 2*d;
    uint32_t u = 0;
    if (m0   == n && n < KK) u |= 0x3F800000u * 0 + ((m0 == n && n < KK) ? 0x3F80u : 0u);
    u = 0;
    if (m0   == n && n < KK) u |= 0x3F80u;
    if (m0+1 == n && n < KK) u |= 0x3F800000u;
    B1[d] = u;
  }

  int cexp = 0;
  f32x16 acc;
  #pragma unroll
  for (int r=0;r<16;++r) acc[r] = 0.f;

  float4 a0,a1,a2, p0,p1,p2, q0,q1,q2;
  auto LD = [&](int it, float4 &r0, float4 &r1, float4 &r2){
    const float* p = rbase + (size_t)it*NST;
    r0 = *(const float4*)(p + off0);
    r1 = *(const float4*)(p + off0 + 4);
    r2 = (hi == 0) ? *(const float4*)(p + 16) : make_float4(0.f,0.f,0.f,0.f);
  };
  auto CONV = [&](const float4 &r0, const float4 &r1, const float4 &r2,
                  u32x4 &A0, u32x4 &A1){
    uint32_t w0 = pk_bf16(fexp2(r0.x*LOG2E), fexp2(r0.y*LOG2E));
    uint32_t w1 = pk_bf16(fexp2(r0.z*LOG2E), fexp2(r0.w*LOG2E));
    uint32_t w2 = pk_bf16(fexp2(r1.x*LOG2E), fexp2(r1.y*LOG2E));
    uint32_t w3 = pk_bf16(fexp2(r1.z*LOG2E), fexp2(r1.w*LOG2E));
    uint32_t w4 = pk_bf16(fexp2(r2.x*LOG2E), fexp2(r2.y*LOG2E));
    uint32_t w5 = pk_bf16(fexp2(r2.z*LOG2E), fexp2(r2.w*LOG2E));
    if (!rowok){ w0=0u; w1=0u; w2=0u; w3=0u; }
    if (!(rowok && hi==0)){ w4=0u; w5=0u; }
    A0[0]=w0; A0[1]=w1; A0[2]=w2; A0[3]=w3;
    A1[0]=w4; A1[1]=w5; A1[2]=0u; A1[3]=0u;
  };
  auto RENORM = [&](){
    float mx = acc[0];
    #pragma unroll
    for (int r=1;r<16;++r) mx = fmaxf(mx, acc[r]);
    mx = fmaxf(mx, __shfl_xor(mx, 32, 64));     // combine with partner rows
    int e = (int)((__float_as_uint(mx) >> 23) & 255) - 127;
    if (e < -100) e = -100;
    float sc = __uint_as_float((uint32_t)(127 - e) << 23);
    #pragma unroll
    for (int r=0;r<16;++r) acc[r] *= sc;
    cexp += e;
  };
  auto C2B = [&](){
    uint32_t x0 = pk_bf16(acc[0],  acc[1]);    // rows (0,1)+4hi
    uint32_t x1 = pk_bf16(acc[2],  acc[3]);    // rows (2,3)+4hi
    uint32_t x2 = pk_bf16(acc[4],  acc[5]);    // rows (8,9)+4hi
    uint32_t x3 = pk_bf16(acc[6],  acc[7]);    // rows (10,11)+4hi
    uint32_t x4 = pk_bf16(acc[8],  acc[9]);    // rows (16,17)+4hi
    uint32_t x5 = pk_bf16(acc[10], acc[11]);   // rows (18,19)+4hi
    uint32_t x6 = pk_bf16(acc[12], acc[13]);   // rows (24,25)+4hi
    uint32_t x7 = pk_bf16(acc[14], acc[15]);   // rows (26,27)+4hi
    pswap(x0,x2); pswap(x1,x3); pswap(x4,x6); pswap(x5,x7);
    B0[0]=x0; B0[1]=x1; B0[2]=x2; B0[3]=x3;    // k = hi*8 + 0..7
    B1[0]=x4; B1[1]=x5; B1[2]=x6; B1[3]=x7;    // k = 16 + hi*8 + 0..7
  };

  LD(0, a0,a1,a2);
  LD((1 < nv) ? 1 : 0, p0,p1,p2);
  q0=a0; q1=a1; q2=a2;
  for (int it=0; it<nv; ++it){
    if (it+2 < nv) LD(it+2, q0,q1,q2);          // depth-2 prefetch
    u32x4 A0, A1; CONV(a0,a1,a2, A0,A1);
    f32x16 z;
    #pragma unroll
    for (int r=0;r<16;++r) z[r] = 0.f;
    acc = mfma_bf16(A0, B0, z);
    acc = mfma_bf16(A1, B1, acc);
    if (it == nv-1) break;                      // keep fp32 acc on last step
    if ((it & 7) == 7) RENORM();                // overflow guard, exact pow2
    C2B();
    a0=p0; a1=p1; a2=p2;
    p0=q0; p1=q1; p2=q2;
  }
  RENORM();

  float* out = wseg + (size_t)task*SEGSTRIDE;
  #pragma unroll
  for (int r=0;r<16;++r){
    int row = (r&3) + 8*(r>>2) + 4*hi;
    if (row < KK && n < KK) out[row*KK + n] = acc[r];
  }
  if (hi==0 && n<KK) ((int*)out)[NST + n] = cexp;
}

// ============ pass 2: serial segment applications (<=SEGS steps) ============
template<int SEGL, int SEGS>
__global__ __launch_bounds__(64,1) void chain_kernel2(
    const float* __restrict__ feats, const float* __restrict__ trans,
    const int* __restrict__ targets, const int* __restrict__ lengths,
    const float* __restrict__ wseg, float* __restrict__ partialA)
{
    constexpr float LOG2E = 1.4426950408889634f;
    constexpr float LN2   = 0.6931471805599453f;
    const int b = blockIdx.x;
    const int lane = threadIdx.x;
    const int len = lengths[b];
    const bool act = lane < KK;
    const int li = act ? lane : 0;

    __shared__ __align__(16) float Ul[KK];

    const float* fb = feats + (size_t)b*TT*NST;
    float a2 = fb[li*KK + START_TAG] * LOG2E;
    float c0 = __uint_as_float(__builtin_amdgcn_readfirstlane(__float_as_uint(a2)));
    float CW = c0;
    float wk = act ? fexp2(a2 - c0) : 0.f;

    const int nseg = (len - 1 + SEGL - 1) / SEGL;

    if (act && nseg > 0){
        float4 mA[5], mB[5];
        int cA = 0, cB = 0;
        auto LDM = [&](int s2, float4 (&m)[5], int& c){
            const float* base = wseg + (size_t)(b*SEGS + s2)*SEGSTRIDE;
            const float4* p4 = (const float4*)(base + li*KK);
            m[0]=p4[0]; m[1]=p4[1]; m[2]=p4[2]; m[3]=p4[3]; m[4]=p4[4];
            c = ((const int*)base)[NST + li];
        };
        auto STEP = [&](float4 (&m)[5], int c){
            int e = (int)((__float_as_uint(wk) >> 23) & 255) - 127;
            int q = __builtin_amdgcn_readfirstlane(c + e);   // approx-max exponent (validated R4)
            Ul[li] = ldexpf(wk, c - q);
            asm volatile("s_waitcnt lgkmcnt(0)" ::: "memory");
            const float4* up = (const float4*)Ul;
            float4 u0 = up[0], u1 = up[1], u2 = up[2], u3 = up[3], u4 = up[4];
            float s0 = m[0].x*u0.x, s1 = m[0].y*u0.y;
            s0 = fmaf(m[0].z,u0.z,s0); s1 = fmaf(m[0].w,u0.w,s1);
            s0 = fmaf(m[1].x,u1.x,s0); s1 = fmaf(m[1].y,u1.y,s1);
            s0 = fmaf(m[1].z,u1.z,s0); s1 = fmaf(m[1].w,u1.w,s1);
            s0 = fmaf(m[2].x,u2.x,s0); s1 = fmaf(m[2].y,u2.y,s1);
            s0 = fmaf(m[2].z,u2.z,s0); s1 = fmaf(m[2].w,u2.w,s1);
            s0 = fmaf(m[3].x,u3.x,s0); s1 = fmaf(m[3].y,u3.y,s1);
            s0 = fmaf(m[3].z,u3.z,s0); s1 = fmaf(m[3].w,u3.w,s1);
            s0 = fmaf(m[4].x,u4.x,s0); s1 = fmaf(m[4].y,u4.y,s1);
            s0 = fmaf(m[4].z,u4.z,s0); s1 = fmaf(m[4].w,u4.w,s1);
            wk = s0 + s1;
            CW += (float)q;
            asm volatile("s_waitcnt lgkmcnt(0)" ::: "memory"); // Ul reads done before next write
        };
        LDM(0, mA, cA);
        for (int s2 = 0; s2 < nseg; ){
            if (s2 + 1 < nseg) LDM(s2 + 1, mB, cB);
            STEP(mA, cA);
            ++s2; if (s2 >= nseg) break;
            if (s2 + 1 < nseg) LDM(s2 + 1, mA, cA);
            STEP(mB, cB);
            ++s2;
        }
    }

    float term = act ? wk * fexp2(trans[STOP_TAG*KK + li] * LOG2E) : 0.f;
    #pragma unroll
    for (int o = 32; o > 0; o >>= 1) term += __shfl_xor(term, o, 64);
    if (lane == 0){
        float lse = LN2 * (CW + flog2(term));
        int last = targets[b*TT + len - 1];
        partialA[b] = lse - trans[STOP_TAG*KK + last];
    }
}

// ============ fallback: proven R1 serial forward ============
__global__ __launch_bounds__(64,1) void fwd_serial(
    const float* __restrict__ feats, const float* __restrict__ trans,
    const int* __restrict__ targets, const int* __restrict__ lengths,
    float* __restrict__ partialA)
{
    constexpr float LOG2E = 1.4426950408889634f;
    constexpr float LN2   = 0.6931471805599453f;
    const int b    = blockIdx.x;
    const int lane = threadIdx.x;
    const int len  = lengths[b];
    const float* fb = feats + (size_t)b * TT * NST;
    __shared__ __align__(16) float alpha[KK];
    __shared__ __align__(16) float xs[KK];
    const bool act = lane < KK;
    const int  li  = act ? lane : 0;
    if (act) alpha[lane] = fb[lane * KK + START_TAG] * LOG2E;
    __syncthreads();
    float4 b0[5], b1[5], b2[5], b3[5];
    auto LOAD = [&](float4* dst, int t){
        int tc = (t < len) ? t : (len - 1);
        const float4* p = (const float4*)(fb + (size_t)tc * NST + li * KK);
        dst[0]=p[0]; dst[1]=p[1]; dst[2]=p[2]; dst[3]=p[3]; dst[4]=p[4];
    };
    auto STEP = [&](const float4* bufv){
        const float4* ap = (const float4*)alpha;
        float a[KK];
        #pragma unroll
        for (int q = 0; q < 5; ++q){
            float4 av = ap[q];
            a[4*q+0]=av.x; a[4*q+1]=av.y; a[4*q+2]=av.z; a[4*q+3]=av.w;
        }
        float v[KK];
        #pragma unroll
        for (int q = 0; q < 5; ++q){
            v[4*q+0] = bufv[q].x * LOG2E + a[4*q+0];
            v[4*q+1] = bufv[q].y * LOG2E + a[4*q+1];
            v[4*q+2] = bufv[q].z * LOG2E + a[4*q+2];
            v[4*q+3] = bufv[q].w * LOG2E + a[4*q+3];
        }
        float m = v[0];
        #pragma unroll
        for (int j = 1; j < KK; ++j) m = fmaxf(m, v[j]);
        float s = 0.f;
        #pragma unroll
        for (int j = 0; j < KK; ++j) s += fexp2(v[j] - m);
        float na = m + flog2(s);
        __syncthreads();
        if (act) alpha[lane] = na;
        __syncthreads();
    };
    LOAD(b0,1); LOAD(b1,2); LOAD(b2,3); LOAD(b3,4);
    int t = 1;
    while (t < len){
        STEP(b0); LOAD(b0, t+4); ++t; if (t >= len) break;
        STEP(b1); LOAD(b1, t+4); ++t; if (t >= len) break;
        STEP(b2); LOAD(b2, t+4); ++t; if (t >= len) break;
        STEP(b3); LOAD(b3, t+4); ++t;
    }
    if (act) xs[lane] = alpha[lane] + trans[STOP_TAG*KK + lane] * LOG2E;
    __syncthreads();
    if (lane == 0){
        float m = xs[0];
        for (int j = 1; j < KK; ++j) m = fmaxf(m, xs[j]);
        float s = 0.f;
        for (int j = 0; j < KK; ++j) s += fexp2(xs[j] - m);
        float lse = LN2 * (m + flog2(s));
        int last_tag = targets[b*TT + (len-1)];
        partialA[b] = lse - trans[STOP_TAG*KK + last_tag];
    }
}

// ============ gold path + final reduce (proven) ============
__global__ __launch_bounds__(256) void gold_kernel(
    const float* __restrict__ feats, const int* __restrict__ targets,
    const int* __restrict__ lengths, float* __restrict__ partialG)
{
    const int b   = blockIdx.x;
    const int tt  = blockIdx.y * 256 + threadIdx.x;
    const int len = lengths[b];
    float val = 0.f;
    if (tt < len){
        int tgt  = targets[b*TT + tt];
        int prev = (tt > 0) ? targets[b*TT + tt - 1] : START_TAG;
        val = feats[((size_t)b*TT + tt)*NST + tgt*KK + prev];
    }
    #pragma unroll
    for (int off = 32; off > 0; off >>= 1) val += __shfl_down(val, off);
    __shared__ float wsum[4];
    if ((threadIdx.x & 63) == 0) wsum[threadIdx.x >> 6] = val;
    __syncthreads();
    if (threadIdx.x == 0)
        partialG[b*gridDim.y + blockIdx.y] = wsum[0]+wsum[1]+wsum[2]+wsum[3];
}

__global__ __launch_bounds__(256) void final_kernel(
    const float* __restrict__ partialA, const float* __restrict__ partialG,
    float* __restrict__ out)
{
    int tid = threadIdx.x;
    float v = partialA[tid] - partialG[tid] - partialG[tid + 256];
    #pragma unroll
    for (int off = 32; off > 0; off >>= 1) v += __shfl_down(v, off);
    __shared__ float wsum[4];
    if ((tid & 63) == 0) wsum[tid >> 6] = v;
    __syncthreads();
    if (tid == 0) out[0] = wsum[0]+wsum[1]+wsum[2]+wsum[3];
}

extern "C" void kernel_launch(void* const* d_in, const int* in_sizes, int n_in,
                              void* d_out, int out_size, void* d_ws, size_t ws_size,
                              hipStream_t stream) {
    const float* feats   = (const float*)d_in[0];
    const float* trans   = (const float*)d_in[1];
    const int*   targets = (const int*)d_in[2];
    const int*   lengths = (const int*)d_in[3];

    float* ws       = (float*)d_ws;
    float* partialA = ws;          // 256 floats
    float* partialG = ws + 256;    // 512 floats
    float* wseg     = ws + WS_SEG_OFF;

    const size_t need64 = (size_t)(WS_SEG_OFF + (size_t)BB*8*SEGSTRIDE) * sizeof(float);

    if (ws_size >= need64){
        seg_mfma<64,8><<<dim3(BB*8), dim3(64), 0, stream>>>(feats, lengths, wseg);
        chain_kernel2<64,8><<<dim3(BB), dim3(64), 0, stream>>>(feats, trans, targets, lengths, wseg, partialA);
    } else {
        fwd_serial<<<dim3(BB), dim3(64), 0, stream>>>(feats, trans, targets, lengths, partialA);
    }
    gold_kernel<<<dim3(BB, 2), dim3(256), 0, stream>>>(feats, targets, lengths, partialG);
    final_kernel<<<dim3(1), dim3(256), 0, stream>>>(partialA, partialG, (float*)d_out);
}